// Round 3
// baseline (187.409 us; speedup 1.0000x reference)
//
#include <hip/hip_runtime.h>
#include <cstdint>
#include <cstddef>

typedef unsigned short u16;
typedef __attribute__((ext_vector_type(8))) short bf16x8;
typedef __attribute__((ext_vector_type(8))) unsigned short u16x8;
typedef __attribute__((ext_vector_type(4))) float f32x4;

// ---------- helpers ----------
__device__ __forceinline__ u16 f2b(float f) {
    union { float f; uint32_t u; } v; v.f = f;
    uint32_t u = v.u;
    uint32_t r = (u + 0x7FFFu + ((u >> 16) & 1u)) >> 16;
    return (u16)r;
}
__device__ __forceinline__ void gload_lds16(const void* g, void* l) {
    __builtin_amdgcn_global_load_lds(
        (const __attribute__((address_space(1))) void*)g,
        (__attribute__((address_space(3))) void*)l,
        16, 0, 0);
}

// ---------- merged prep ----------
// blocks [0,2048):      features f32->bf16 (2048 elems/block)
// blocks [2048,3072):   W3 [2048,1024] f32->bf16 (straight convert; consumed as BT)
// blocks [3072,5120):   W1 [1024,2048] -> W1T [2048,1024] bf16
// blocks [5120,9216):   W2 [2048,2048] -> W2T
// blocks [9216,9728):   Wh [1024,512] -> WhT [512,1024]
// blocks [9728,9730):   b34[j] = sum_k b3[k]*Wh[k][j] + bh[j]  (f32)
__global__ __launch_bounds__(256) void prep_kernel(
    const float* __restrict__ feat, u16* __restrict__ featB,
    const float* __restrict__ W1, u16* __restrict__ W1T,
    const float* __restrict__ W2, u16* __restrict__ W2T,
    const float* __restrict__ W3, u16* __restrict__ W3c,
    const float* __restrict__ Wh, u16* __restrict__ WhT,
    const float* __restrict__ b3, const float* __restrict__ bh,
    float* __restrict__ b34) {
    __shared__ float tile[32][33];
    const int b = blockIdx.x, tid = threadIdx.x;

    if (b < 3072) {  // straight f32 -> bf16 convert, 8 elems/thread
        const float* in = (b < 2048) ? feat : W3;
        u16* outp = (b < 2048) ? featB : W3c;
        int bb = (b < 2048) ? b : (b - 2048);
        size_t base = (size_t)bb * 2048 + (size_t)tid * 8;
        const float4* p = (const float4*)(in + base);
        float4 a = p[0], c = p[1];
        u16x8 o;
        o[0] = f2b(a.x); o[1] = f2b(a.y); o[2] = f2b(a.z); o[3] = f2b(a.w);
        o[4] = f2b(c.x); o[5] = f2b(c.y); o[6] = f2b(c.z); o[7] = f2b(c.w);
        *(u16x8*)(outp + base) = o;
        return;
    }
    if (b >= 9728) {  // b34
        int j = (b - 9728) * 256 + tid;  // [0,512)
        float s = bh[j];
        for (int k = 0; k < 1024; ++k)
            s += b3[k] * Wh[(size_t)k * 512 + j];
        b34[j] = s;
        return;
    }
    // transposes
    const float* in; u16* outp; int K, N, t;
    if (b < 5120)      { t = b - 3072; in = W1; outp = W1T; K = 1024; N = 2048; }
    else if (b < 9216) { t = b - 5120; in = W2; outp = W2T; K = 2048; N = 2048; }
    else               { t = b - 9216; in = Wh; outp = WhT; K = 1024; N = 512;  }
    const int ntx = N >> 5;
    const int n0 = (t % ntx) * 32, k0 = (t / ntx) * 32;
    const int tx = tid & 31, ty = tid >> 5;
#pragma unroll
    for (int r = ty; r < 32; r += 8)
        tile[r][tx] = in[(size_t)(k0 + r) * N + n0 + tx];
    __syncthreads();
#pragma unroll
    for (int r = ty; r < 32; r += 8)
        outp[(size_t)(n0 + r) * K + k0 + tx] = f2b(tile[tx][r]);
}

// ---------- GEMM body (128x128 tile, BK=64, 4 waves, 4x4 16x16x32 MFMA) ----------
// C[M,N] = act(A[M,K] @ BT[N,K]^T + bias); bias may be null; relu runtime flag.
__device__ __forceinline__ void gemm_body(
    const u16* __restrict__ A, const u16* __restrict__ BT,
    const float* __restrict__ bias, u16* __restrict__ C,
    int M, int N, int K, int relu, int bx, int by,
    u16* sA, u16* sB) {
    const int tid = threadIdx.x;
    const int lane = tid & 63;
    const int w = tid >> 6;
    const int wm = w >> 1, wn = w & 1;
    const int lr = lane & 15, lg = lane >> 4;
    const int rowBase = by * 128;
    const int colBase = bx * 128;

    f32x4 acc[4][4] = {};
    const int nk = K >> 6;
    const int ci = tid;

    for (int kt = 0; kt < nk; ++kt) {
        const int kb = kt << 6;
#pragma unroll
        for (int j = 0; j < 4; ++j) {
            int c = j * 256 + ci;
            int row = c >> 3, ch = c & 7;
            const u16* ga = A + (size_t)(rowBase + row) * K + kb + ch * 8;
            gload_lds16(ga, (char*)sA + (size_t)(j * 256 + (w << 6)) * 16);
            const u16* gb = BT + (size_t)(colBase + row) * K + kb + ch * 8;
            gload_lds16(gb, (char*)sB + (size_t)(j * 256 + (w << 6)) * 16);
        }
        __syncthreads();
#pragma unroll
        for (int kk = 0; kk < 2; ++kk) {
            bf16x8 af[4], bfr[4];
#pragma unroll
            for (int m = 0; m < 4; ++m)
                af[m] = *(const bf16x8*)&sA[(wm * 64 + m * 16 + lr) * 64 + kk * 32 + lg * 8];
#pragma unroll
            for (int n = 0; n < 4; ++n)
                bfr[n] = *(const bf16x8*)&sB[(wn * 64 + n * 16 + lr) * 64 + kk * 32 + lg * 8];
#pragma unroll
            for (int m = 0; m < 4; ++m)
#pragma unroll
                for (int n = 0; n < 4; ++n)
                    acc[m][n] = __builtin_amdgcn_mfma_f32_16x16x32_bf16(
                        af[m], bfr[n], acc[m][n], 0, 0, 0);
        }
        __syncthreads();
    }

#pragma unroll
    for (int n = 0; n < 4; ++n) {
        int col = colBase + wn * 64 + n * 16 + lr;
        float bv = bias ? bias[col] : 0.f;
#pragma unroll
        for (int m = 0; m < 4; ++m) {
            int row0 = rowBase + wm * 64 + m * 16 + lg * 4;
#pragma unroll
            for (int i = 0; i < 4; ++i) {
                float v = acc[m][n][i] + bv;
                if (relu) v = v > 0.f ? v : 0.f;
                C[(size_t)(row0 + i) * N + col] = f2b(v);
            }
        }
    }
}

// ---------- plain GEMM ----------
__global__ __launch_bounds__(256)
void gemm_bt(const u16* __restrict__ A, const u16* __restrict__ BT,
             const float* __restrict__ bias, u16* __restrict__ C,
             int M, int N, int K, int relu) {
    __shared__ __align__(16) u16 sA[128 * 64];
    __shared__ __align__(16) u16 sB[128 * 64];
    gemm_body(A, BT, bias, C, M, N, K, relu, blockIdx.x, blockIdx.y, sA, sB);
}

// ---------- grouped GEMM: blocks < nblk0 run problem 0, rest run problem 1 ----------
__global__ __launch_bounds__(256)
void gemm_grouped(
    const u16* A0, const u16* B0, const float* bias0, u16* C0,
    int M0, int N0, int K0, int relu0, int nblk0,
    const u16* A1, const u16* B1, const float* bias1, u16* C1,
    int M1, int N1, int K1, int relu1) {
    __shared__ __align__(16) u16 sA[128 * 64];
    __shared__ __align__(16) u16 sB[128 * 64];
    int b = blockIdx.x;
    if (b < nblk0) {
        int nbx = N0 >> 7;
        gemm_body(A0, B0, bias0, C0, M0, N0, K0, relu0, b % nbx, b / nbx, sA, sB);
    } else {
        int g = b - nblk0;
        int nbx = N1 >> 7;
        gemm_body(A1, B1, bias1, C1, M1, N1, K1, relu1, g % nbx, g / nbx, sA, sB);
    }
}

// ---------- fused GEMM + row-dot ----------
// out[row] += sum_col (A[row,:]@BT[col,:] + bias[col]) * wmat[col, row]
__global__ __launch_bounds__(256)
void gemm_dot(const u16* __restrict__ A, const u16* __restrict__ BT,
              const float* __restrict__ bias, const float* __restrict__ wmat,
              float* __restrict__ out, int M, int N, int K) {
    __shared__ __align__(16) u16 sA[128 * 64];
    __shared__ __align__(16) u16 sB[128 * 64];
    const int tid = threadIdx.x;
    const int lane = tid & 63;
    const int wv = tid >> 6;
    const int wm = wv >> 1, wn = wv & 1;
    const int lr = lane & 15, lg = lane >> 4;
    const int rowBase = blockIdx.y * 128;
    const int colBase = blockIdx.x * 128;

    f32x4 acc[4][4] = {};
    const int nk = K >> 6;
    const int ci = tid;

    for (int kt = 0; kt < nk; ++kt) {
        const int kb = kt << 6;
#pragma unroll
        for (int j = 0; j < 4; ++j) {
            int c = j * 256 + ci;
            int row = c >> 3, ch = c & 7;
            const u16* ga = A + (size_t)(rowBase + row) * K + kb + ch * 8;
            gload_lds16(ga, (char*)sA + (size_t)(j * 256 + (wv << 6)) * 16);
            const u16* gb = BT + (size_t)(colBase + row) * K + kb + ch * 8;
            gload_lds16(gb, (char*)sB + (size_t)(j * 256 + (wv << 6)) * 16);
        }
        __syncthreads();
#pragma unroll
        for (int kk = 0; kk < 2; ++kk) {
            bf16x8 af[4], bfr[4];
#pragma unroll
            for (int m = 0; m < 4; ++m)
                af[m] = *(const bf16x8*)&sA[(wm * 64 + m * 16 + lr) * 64 + kk * 32 + lg * 8];
#pragma unroll
            for (int n = 0; n < 4; ++n)
                bfr[n] = *(const bf16x8*)&sB[(wn * 64 + n * 16 + lr) * 64 + kk * 32 + lg * 8];
#pragma unroll
            for (int m = 0; m < 4; ++m)
#pragma unroll
                for (int n = 0; n < 4; ++n)
                    acc[m][n] = __builtin_amdgcn_mfma_f32_16x16x32_bf16(
                        af[m], bfr[n], acc[m][n], 0, 0, 0);
        }
        __syncthreads();
    }

    // epilogue: logits * w[col][row], reduce over cols
    float psum[4][4] = {};
#pragma unroll
    for (int n = 0; n < 4; ++n) {
        int col = colBase + wn * 64 + n * 16 + lr;
        float bv = bias[col];
        const float* wc = wmat + (size_t)col * M;
#pragma unroll
        for (int m = 0; m < 4; ++m) {
            int row0 = rowBase + wm * 64 + m * 16 + lg * 4;
#pragma unroll
            for (int i = 0; i < 4; ++i) {
                float v = acc[m][n][i] + bv;
                psum[m][i] += v * wc[row0 + i];
            }
        }
    }
#pragma unroll
    for (int m = 0; m < 4; ++m)
#pragma unroll
        for (int i = 0; i < 4; ++i) {
#pragma unroll
            for (int mask = 1; mask < 16; mask <<= 1)
                psum[m][i] += __shfl_xor(psum[m][i], mask);
        }
    if (lr == 0) {
#pragma unroll
        for (int m = 0; m < 4; ++m) {
            int row0 = rowBase + wm * 64 + m * 16 + lg * 4;
#pragma unroll
            for (int i = 0; i < 4; ++i)
                atomicAdd(&out[row0 + i], psum[m][i]);
        }
    }
}

// ---------- launch ----------
extern "C" void kernel_launch(void* const* d_in, const int* in_sizes, int n_in,
                              void* d_out, int out_size, void* d_ws, size_t ws_size,
                              hipStream_t stream) {
    const float* features = (const float*)d_in[0];  // [4096,1024]
    const float* W1 = (const float*)d_in[1];        // [1024,2048]
    const float* b1 = (const float*)d_in[2];
    const float* W2 = (const float*)d_in[3];        // [2048,2048]
    const float* b2 = (const float*)d_in[4];
    const float* W3 = (const float*)d_in[5];        // [2048,1024]
    const float* b3 = (const float*)d_in[6];
    const float* Wh = (const float*)d_in[7];        // [1024,512]
    const float* bh = (const float*)d_in[8];
    const float* w  = (const float*)d_in[9];        // [512,4096]
    float* out = (float*)d_out;

    const int N = 4096, D_in = 1024, H1 = 2048, H2 = 2048, H3 = 1024, D_out = 512;

    size_t off = 0;
    auto alloc = [&](size_t bytes) {
        void* p = (char*)d_ws + off;
        off += (bytes + 255) & ~(size_t)255;
        return p;
    };
    u16* featB = (u16*)alloc((size_t)N * D_in * 2);       // 8MB
    u16* W1T   = (u16*)alloc((size_t)H1 * D_in * 2);      // 4MB
    u16* W2T   = (u16*)alloc((size_t)H2 * H1 * 2);        // 8MB
    u16* W3c   = (u16*)alloc((size_t)H2 * H3 * 2);        // 4MB (row-major bf16)
    u16* WhT   = (u16*)alloc((size_t)D_out * H3 * 2);     // 1MB
    u16* W34T  = (u16*)alloc((size_t)D_out * H2 * 2);     // 2MB
    float* b34 = (float*)alloc((size_t)D_out * 4);        // 2KB
    u16* h1    = (u16*)alloc((size_t)N * H1 * 2);         // 16MB
    u16* h2    = (u16*)alloc((size_t)N * H2 * 2);         // 16MB

    // out accumulated via atomics -> zero it
    hipMemsetAsync(out, 0, (size_t)N * sizeof(float), stream);

    // 1. merged prep: cvt(features), cvt(W3), T(W1), T(W2), T(Wh), b34
    prep_kernel<<<9730, 256, 0, stream>>>(features, featB, W1, W1T, W2, W2T,
                                          W3, W3c, Wh, WhT, b3, bh, b34);

    // 2. grouped: GEMM1 (h1 = relu(featB@W1T^T + b1), 512 blocks)
    //           + W34T = WhT @ W3c^T  (i.e. (W3@Wh)^T, 64 blocks), both K=1024
    gemm_grouped<<<512 + 64, 256, 0, stream>>>(
        featB, W1T, b1, h1, N, H1, D_in, 1, 512,
        WhT, W3c, nullptr, W34T, D_out, H2, H3, 0);

    // 3. GEMM2: h2 = relu(h1 @ W2T^T + b2)
    gemm_bt<<<dim3(H2 / 128, N / 128), 256, 0, stream>>>(h1, W2T, b2, h2, N, H2, H1, 1);

    // 4. fused: out[n] = sum_j (h2@W34T^T + b34)[n][j] * w[j][n]
    gemm_dot<<<dim3(D_out / 128, N / 128), 256, 0, stream>>>(h2, W34T, b34, w, out, N, D_out, H2);
}

// Round 4
// 156.169 us; speedup vs baseline: 1.2000x; 1.2000x over previous
//
#include <hip/hip_runtime.h>
#include <cstdint>
#include <cstddef>

typedef unsigned short u16;
typedef __attribute__((ext_vector_type(8))) short bf16x8;
typedef __attribute__((ext_vector_type(8))) unsigned short u16x8;
typedef __attribute__((ext_vector_type(4))) float f32x4;

// ---------- helpers ----------
__device__ __forceinline__ u16 f2b(float f) {
    union { float f; uint32_t u; } v; v.f = f;
    uint32_t u = v.u;
    uint32_t r = (u + 0x7FFFu + ((u >> 16) & 1u)) >> 16;
    return (u16)r;
}
__device__ __forceinline__ float b2f(u16 b) {
    union { uint32_t u; float f; } v; v.u = ((uint32_t)b) << 16;
    return v.f;
}
__device__ __forceinline__ void gload_lds16(const void* g, void* l) {
    __builtin_amdgcn_global_load_lds(
        (const __attribute__((address_space(1))) void*)g,
        (__attribute__((address_space(3))) void*)l,
        16, 0, 0);
}

// ---------- building blocks ----------
// straight f32 -> bf16, 2048 elems per block (256 thr x 8)
__device__ __forceinline__ void cvt_block(const float* __restrict__ in,
                                          u16* __restrict__ outp, int bb, int tid) {
    size_t base = (size_t)bb * 2048 + (size_t)tid * 8;
    const float4* p = (const float4*)(in + base);
    float4 a = p[0], c = p[1];
    u16x8 o;
    o[0] = f2b(a.x); o[1] = f2b(a.y); o[2] = f2b(a.z); o[3] = f2b(a.w);
    o[4] = f2b(c.x); o[5] = f2b(c.y); o[6] = f2b(c.z); o[7] = f2b(c.w);
    *(u16x8*)(outp + base) = o;
}

// 32x32 tile transpose: in[K][N] f32 -> out[N][K] bf16, tile index t
__device__ __forceinline__ void transpose_block(const float* __restrict__ in,
                                                u16* __restrict__ outp,
                                                int K, int N, int t, int tid,
                                                float (*tile)[33]) {
    const int ntx = N >> 5;
    const int n0 = (t % ntx) * 32, k0 = (t / ntx) * 32;
    const int tx = tid & 31, ty = tid >> 5;
#pragma unroll
    for (int r = ty; r < 32; r += 8)
        tile[r][tx] = in[(size_t)(k0 + r) * N + n0 + tx];
    __syncthreads();
#pragma unroll
    for (int r = ty; r < 32; r += 8)
        outp[(size_t)(n0 + r) * K + k0 + tx] = f2b(tile[tx][r]);
}

// GEMM body: C[M,N](bf16) = act(A[M,K]bf16 @ BT[N,K]bf16^T + bias)
// 128x128 tile, BK=64, 4 waves (2x2), 4x4 16x16x32 MFMA fragments.
// relu/bias are call-site literals -> const-folded after inlining.
__device__ __forceinline__ void gemm_body(
    const u16* __restrict__ A, const u16* __restrict__ BT,
    const float* __restrict__ bias, u16* __restrict__ C,
    int N, int K, int relu, int bx, int by, u16* sA, u16* sB) {
    const int tid = threadIdx.x;
    const int lane = tid & 63;
    const int w = tid >> 6;
    const int wm = w >> 1, wn = w & 1;
    const int lr = lane & 15, lg = lane >> 4;
    const int rowBase = by * 128;
    const int colBase = bx * 128;

    f32x4 acc[4][4] = {};
    const int nk = K >> 6;
    const int ci = tid;

    for (int kt = 0; kt < nk; ++kt) {
        const int kb = kt << 6;
#pragma unroll
        for (int j = 0; j < 4; ++j) {
            int c = j * 256 + ci;
            int row = c >> 3, ch = c & 7;
            const u16* ga = A + (size_t)(rowBase + row) * K + kb + ch * 8;
            gload_lds16(ga, (char*)sA + (size_t)(j * 256 + (w << 6)) * 16);
            const u16* gb = BT + (size_t)(colBase + row) * K + kb + ch * 8;
            gload_lds16(gb, (char*)sB + (size_t)(j * 256 + (w << 6)) * 16);
        }
        __syncthreads();
#pragma unroll
        for (int kk = 0; kk < 2; ++kk) {
            bf16x8 af[4], bfr[4];
#pragma unroll
            for (int m = 0; m < 4; ++m)
                af[m] = *(const bf16x8*)&sA[(wm * 64 + m * 16 + lr) * 64 + kk * 32 + lg * 8];
#pragma unroll
            for (int n = 0; n < 4; ++n)
                bfr[n] = *(const bf16x8*)&sB[(wn * 64 + n * 16 + lr) * 64 + kk * 32 + lg * 8];
#pragma unroll
            for (int m = 0; m < 4; ++m)
#pragma unroll
                for (int n = 0; n < 4; ++n)
                    acc[m][n] = __builtin_amdgcn_mfma_f32_16x16x32_bf16(
                        af[m], bfr[n], acc[m][n], 0, 0, 0);
        }
        __syncthreads();
    }

#pragma unroll
    for (int n = 0; n < 4; ++n) {
        int col = colBase + wn * 64 + n * 16 + lr;
        float bv = bias ? bias[col] : 0.f;
#pragma unroll
        for (int m = 0; m < 4; ++m) {
            int row0 = rowBase + wm * 64 + m * 16 + lg * 4;
#pragma unroll
            for (int i = 0; i < 4; ++i) {
                float v = acc[m][n][i] + bv;
                if (relu) v = v > 0.f ? v : 0.f;
                C[(size_t)(row0 + i) * N + col] = f2b(v);
            }
        }
    }
}

// ---------- prep1: converts + transposes + b34 (7682 blocks) ----------
// [0,2048)      feat [4096,1024] f32->bf16
// [2048,3072)   W3   [2048,1024] f32->bf16 (row-major, BT operand of W34-GEMM)
// [3072,5120)   W1   [1024,2048] -> W1T [2048,1024] bf16
// [5120,5632)   Wh   [1024,512]  -> WhT [512,1024] bf16
// [5632,7680)   w    [512,4096]  -> wTb [4096,512] bf16
// [7680,7682)   b34[j] = b3 . Wh[:,j] + bh[j]   (f32)
__global__ __launch_bounds__(256) void prep1_kernel(
    const float* __restrict__ feat, u16* __restrict__ featB,
    const float* __restrict__ W1, u16* __restrict__ W1T,
    const float* __restrict__ W3, u16* __restrict__ W3c,
    const float* __restrict__ Wh, u16* __restrict__ WhT,
    const float* __restrict__ w, u16* __restrict__ wTb,
    const float* __restrict__ b3, const float* __restrict__ bh,
    float* __restrict__ b34) {
    __shared__ float tile[32][33];
    const int b = blockIdx.x, tid = threadIdx.x;
    if (b < 2048)      { cvt_block(feat, featB, b, tid); return; }
    if (b < 3072)      { cvt_block(W3, W3c, b - 2048, tid); return; }
    if (b < 5120)      { transpose_block(W1, W1T, 1024, 2048, b - 3072, tid, tile); return; }
    if (b < 5632)      { transpose_block(Wh, WhT, 1024, 512, b - 5120, tid, tile); return; }
    if (b < 7680)      { transpose_block(w, wTb, 512, 4096, b - 5632, tid, tile); return; }
    {   // b34
        int j = (b - 7680) * 256 + tid;  // [0,512)
        float s = bh[j];
        for (int k = 0; k < 1024; ++k)
            s += b3[k] * Wh[(size_t)k * 512 + j];
        b34[j] = s;
    }
}

// ---------- groupedA (4688 blocks) ----------
// [0,512)     GEMM1: h1 = relu(featB @ W1T^T + b1)   M=4096 N=2048 K=1024
// [512,576)   W34  = W3c @ WhT^T                     M=2048 N=512  K=1024
// [576,592)   c[n] = b34 . w[:,n]                    (f32, 4096 threads)
// [592,4688)  W2 [2048,2048] -> W2T bf16 (4096 tiles)
__global__ __launch_bounds__(256) void groupedA_kernel(
    const u16* __restrict__ featB, const u16* __restrict__ W1T,
    const float* __restrict__ b1, u16* __restrict__ h1,
    const u16* __restrict__ W3c, const u16* __restrict__ WhT, u16* __restrict__ W34,
    const float* __restrict__ b34, const float* __restrict__ w, float* __restrict__ c,
    const float* __restrict__ W2, u16* __restrict__ W2T) {
    __shared__ __align__(16) u16 sA[128 * 64];
    __shared__ __align__(16) u16 sB[128 * 64];
    const int b = blockIdx.x, tid = threadIdx.x;
    if (b < 512) {
        gemm_body(featB, W1T, b1, h1, 2048, 1024, 1, b % 16, b / 16, sA, sB);
    } else if (b < 576) {
        int g = b - 512;
        gemm_body(W3c, WhT, nullptr, W34, 512, 1024, 0, g % 4, g / 4, sA, sB);
    } else if (b < 592) {
        int n = (b - 576) * 256 + tid;  // [0,4096)
        float s = 0.f;
        for (int j = 0; j < 512; ++j)
            s += b34[j] * w[(size_t)j * 4096 + n];
        c[n] = s;
    } else {
        transpose_block(W2, W2T, 2048, 2048, b - 592, tid, (float(*)[33])sA);
    }
}

// ---------- groupedB (1024 blocks) ----------
// [0,512)     GEMM2: h2 = relu(h1 @ W2T^T + b2)   M=4096 N=2048 K=2048
// [512,1024)  UT = wTb @ W34^T                    M=4096 N=2048 K=512
//             UT[n,k] = sum_j w[j,n]*W34[k,j]
__global__ __launch_bounds__(256) void groupedB_kernel(
    const u16* __restrict__ h1, const u16* __restrict__ W2T,
    const float* __restrict__ b2, u16* __restrict__ h2,
    const u16* __restrict__ wTb, const u16* __restrict__ W34, u16* __restrict__ UT) {
    __shared__ __align__(16) u16 sA[128 * 64];
    __shared__ __align__(16) u16 sB[128 * 64];
    const int b = blockIdx.x;
    if (b < 512) {
        gemm_body(h1, W2T, b2, h2, 2048, 2048, 1, b % 16, b / 16, sA, sB);
    } else {
        int g = b - 512;
        gemm_body(wTb, W34, nullptr, UT, 2048, 512, 0, g % 16, g / 16, sA, sB);
    }
}

// ---------- final dot: out[n] = c[n] + sum_k h2[n,k]*UT[n,k] ----------
__global__ __launch_bounds__(256) void dot_kernel(
    const u16* __restrict__ h2, const u16* __restrict__ UT,
    const float* __restrict__ c, float* __restrict__ out) {
    const int n = blockIdx.x * 4 + (threadIdx.x >> 6);
    const int lane = threadIdx.x & 63;
    const u16* hrow = h2 + (size_t)n * 2048;
    const u16* urow = UT + (size_t)n * 2048;
    float s = 0.f;
#pragma unroll
    for (int chk = 0; chk < 4; ++chk) {
        int o = chk * 512 + lane * 8;
        u16x8 hv = *(const u16x8*)(hrow + o);
        u16x8 uv = *(const u16x8*)(urow + o);
#pragma unroll
        for (int t = 0; t < 8; ++t) s += b2f(hv[t]) * b2f(uv[t]);
    }
#pragma unroll
    for (int off = 32; off; off >>= 1) s += __shfl_xor(s, off);
    if (lane == 0) out[n] = c[n] + s;
}

// ---------- launch ----------
extern "C" void kernel_launch(void* const* d_in, const int* in_sizes, int n_in,
                              void* d_out, int out_size, void* d_ws, size_t ws_size,
                              hipStream_t stream) {
    const float* features = (const float*)d_in[0];  // [4096,1024]
    const float* W1 = (const float*)d_in[1];        // [1024,2048]
    const float* b1 = (const float*)d_in[2];
    const float* W2 = (const float*)d_in[3];        // [2048,2048]
    const float* b2 = (const float*)d_in[4];
    const float* W3 = (const float*)d_in[5];        // [2048,1024]
    const float* b3 = (const float*)d_in[6];
    const float* Wh = (const float*)d_in[7];        // [1024,512]
    const float* bh = (const float*)d_in[8];
    const float* w  = (const float*)d_in[9];        // [512,4096]
    float* out = (float*)d_out;

    size_t off = 0;
    auto alloc = [&](size_t bytes) {
        void* p = (char*)d_ws + off;
        off += (bytes + 255) & ~(size_t)255;
        return p;
    };
    // dead after groupedA (UT aliases this 16MB region during groupedB/dot):
    u16* featB = (u16*)alloc((size_t)4096 * 1024 * 2);   // 8MB
    u16* W1T   = (u16*)alloc((size_t)2048 * 1024 * 2);   // 4MB
    u16* W3c   = (u16*)alloc((size_t)2048 * 1024 * 2);   // 4MB
    u16* UT    = featB;                                  // [4096,2048] bf16 = 16MB alias
    // live into groupedB / dot:
    u16* WhT   = (u16*)alloc((size_t)512 * 1024 * 2);    // 1MB
    u16* W2T   = (u16*)alloc((size_t)2048 * 2048 * 2);   // 8MB
    u16* wTb   = (u16*)alloc((size_t)4096 * 512 * 2);    // 4MB
    u16* W34   = (u16*)alloc((size_t)2048 * 512 * 2);    // 2MB
    float* b34 = (float*)alloc((size_t)512 * 4);
    float* c   = (float*)alloc((size_t)4096 * 4);
    u16* h1    = (u16*)alloc((size_t)4096 * 2048 * 2);   // 16MB
    u16* h2    = (u16*)alloc((size_t)4096 * 2048 * 2);   // 16MB

    // 1. prep: converts + transposes + b34
    prep1_kernel<<<7682, 256, 0, stream>>>(features, featB, W1, W1T, W3, W3c,
                                           Wh, WhT, w, wTb, b3, bh, b34);

    // 2. groupedA: GEMM1 || W34-GEMM || c || W2-transpose
    groupedA_kernel<<<4688, 256, 0, stream>>>(featB, W1T, b1, h1,
                                              W3c, WhT, W34,
                                              b34, w, c, W2, W2T);

    // 3. groupedB: GEMM2 || UT-GEMM
    groupedB_kernel<<<1024, 256, 0, stream>>>(h1, W2T, b2, h2, wTb, W34, UT);

    // 4. final row-dot
    dot_kernel<<<1024, 256, 0, stream>>>(h2, UT, c, out);
}